// Round 8
// baseline (63.759 us; speedup 1.0000x reference)
//
#include <hip/hip_runtime.h>
#include <math.h>

// Problem constants (fixed by setup_inputs)
//   h: (32, 512, 320) f32, a_link/b_link: (256, 64) f32, rollout: 1 (unused)
// Outputs: A_out (32,512,512) f32  then probs (32,) f32, concatenated.
#define BATCH   32
#define NPTS    512
#define FDIM    320
#define FOBS    256
#define DK      64
#define MROWS   (BATCH * NPTS)
#define A_ELEMS ((size_t)BATCH * NPTS * NPTS)  // 8388608

typedef __bf16  bf16x8 __attribute__((ext_vector_type(8)));
typedef float   f32x4  __attribute__((ext_vector_type(4)));
typedef ushort  u16x4  __attribute__((ext_vector_type(4)));

__device__ __forceinline__ ushort f2bf(float f) {   // RNE f32 -> bf16
    unsigned u = __builtin_bit_cast(unsigned, f);
    return (ushort)((u + 0x7fffu + ((u >> 16) & 1u)) >> 16);
}
__device__ __forceinline__ unsigned pbf2(float a, float b) {
    return (unsigned)f2bf(a) | ((unsigned)f2bf(b) << 16);
}
__device__ __forceinline__ bf16x8 ld_bf8(const ushort* p) {
    return __builtin_bit_cast(bf16x8, *reinterpret_cast<const uint4*>(p));
}
// f32 row slice (8 floats) -> bf16x8
__device__ __forceinline__ bf16x8 cvt8(const float* p) {
    float4 v0 = *reinterpret_cast<const float4*>(p);
    float4 v1 = *reinterpret_cast<const float4*>(p + 4);
    uint4 u;
    u.x = pbf2(v0.x, v0.y); u.y = pbf2(v0.z, v0.w);
    u.z = pbf2(v1.x, v1.y); u.w = pbf2(v1.z, v1.w);
    return __builtin_bit_cast(bf16x8, u);
}

// ---------------------------------------------------------------------------
// K0: Wt[n][k] = bf16( n<64 ? a_link[k][n] : b_link[k][n-64] )   (128 x 256)
// ---------------------------------------------------------------------------
__global__ __launch_bounds__(256) void k0_wt(const float* __restrict__ al,
                                             const float* __restrict__ bl,
                                             ushort* __restrict__ wt) {
    const int n = blockIdx.x;            // 0..127
    const int k = threadIdx.x;           // 0..255
    const float* src = (n < 64) ? al : bl;
    const int nn = n & 63;
    wt[(size_t)n * FOBS + k] = f2bf(src[(size_t)k * DK + nn]);
}

// ---------------------------------------------------------------------------
// KU (fused): grid 512 = (xcd-swizzled) 32 b x 8 it x 2 jh. Per block:
//   Phase A: project hi rows [i0,i0+64) (k1's verified MFMA pattern) -> LDS
//            (XOR-swizzled, G4), barrier, hoist hi B-frags to registers.
//   Per jt (4x): project hj rows in-wave, shuffle D-frags -> A-frag layout
//            (4-lane groups, 16 shfl + 8 sel), 8 logits MFMA (k2's verified
//            pattern), fused epilogue: A=(x>0)|diag f32x4 NT store, lsum.
//   Tail: block-reduce lsum -> partials[b*16 + it*2 + jh].
//   No hi/hj global round-trip, no fences, no atomics (R5/R7 lessons).
// ---------------------------------------------------------------------------
__global__ __launch_bounds__(256, 3) void kU(const float* __restrict__ h,
                                             const ushort* __restrict__ wt,
                                             float* __restrict__ Aout,
                                             float* __restrict__ partials) {
    __shared__ ushort hi_lds[64][72];    // row stride 144 B (16B-aligned)
    __shared__ float red[4];

    const int id  = blockIdx.x;
    const int sub = id >> 3;
    const int b   = (id & 7) * 4 + (sub >> 4);   // XCD owns 4 whole batches
    const int rem = sub & 15;
    const int it  = rem >> 1, jh = rem & 1;
    const int i0 = it * 64, jbase = jh * 256;    // batch-relative

    const int t  = threadIdx.x;
    const int w  = t >> 6;
    const int l  = t & 63;
    const int lr = l & 15;
    const int lg = l >> 4;

    const float* hb = h + (size_t)b * NPTS * FDIM;

    // ---- Phase A: hi rows [i0+16w, i0+16w+16) ----
    {
        const float* hrow = hb + (size_t)(i0 + 16 * w + lr) * FDIM;
        bf16x8 hfr[8];
#pragma unroll
        for (int ks = 0; ks < 8; ++ks) hfr[ks] = cvt8(hrow + ks * 32 + lg * 8);

        f32x4 acc[4];
#pragma unroll
        for (int cf = 0; cf < 4; ++cf) acc[cf] = (f32x4){0.f, 0.f, 0.f, 0.f};
#pragma unroll
        for (int ks = 0; ks < 8; ++ks)
#pragma unroll
            for (int cf = 0; cf < 4; ++cf) {
                bf16x8 afr = ld_bf8(&wt[(size_t)(16 * cf + lr) * FOBS + ks * 32 + lg * 8]);
                acc[cf] = __builtin_amdgcn_mfma_f32_16x16x32_bf16(afr, hfr[ks], acc[cf], 0, 0, 0);
            }
        // D: lane holds hi[16w+lr][16cf+4lg+r] -> swizzled 8B LDS writes
        const int row = 16 * w + lr;
        const int xr  = (row & 3) << 4;
#pragma unroll
        for (int cf = 0; cf < 4; ++cf) {
            u16x4 v;
#pragma unroll
            for (int r = 0; r < 4; ++r) v[r] = f2bf(acc[cf][r]);
            int colb = (32 * cf + 8 * lg) ^ xr;
            *reinterpret_cast<u16x4*>(reinterpret_cast<char*>(&hi_lds[row][0]) + colb) = v;
        }
    }
    __syncthreads();

    // hoist hi B-frags: lane needs hi[16itt+lr][32ks+8lg .. +8)
    bf16x8 hifr[4][2];
#pragma unroll
    for (int itt = 0; itt < 4; ++itt)
#pragma unroll
        for (int ks = 0; ks < 2; ++ks) {
            int row  = 16 * itt + lr;
            int colb = (64 * ks + 16 * lg) ^ ((row & 3) << 4);
            hifr[itt][ks] = *reinterpret_cast<bf16x8*>(
                reinterpret_cast<char*>(&hi_lds[row][0]) + colb);
        }

    float lsum = 0.f;
    const int s0 = lr + 16 * (2 * (lg & 1));   // shfl sources (4-lane groups)
    const int s1 = s0 + 16;
    const bool hicf = (lg >> 1) != 0;

    for (int jt = 0; jt < 4; ++jt) {
        const int j0 = jbase + jt * 64;

        // ---- project hj rows [j0+16w, +16) (in-wave) ----
        f32x4 acc[4];
#pragma unroll
        for (int cf = 0; cf < 4; ++cf) acc[cf] = (f32x4){0.f, 0.f, 0.f, 0.f};
        {
            const float* hrow = hb + (size_t)(j0 + 16 * w + lr) * FDIM;
#pragma unroll
            for (int ks = 0; ks < 8; ++ks) {
                bf16x8 hfr = cvt8(hrow + ks * 32 + lg * 8);
#pragma unroll
                for (int cf = 0; cf < 4; ++cf) {
                    bf16x8 afr = ld_bf8(&wt[(size_t)(64 + 16 * cf + lr) * FOBS + ks * 32 + lg * 8]);
                    acc[cf] = __builtin_amdgcn_mfma_f32_16x16x32_bf16(afr, hfr, acc[cf], 0, 0, 0);
                }
            }
        }
        // pack: lane (lr,lg) holds hj[16w+lr][16cf+4lg+{0..3}]
        unsigned dA[4], dB[4];
#pragma unroll
        for (int cf = 0; cf < 4; ++cf) {
            dA[cf] = pbf2(acc[cf][0], acc[cf][1]);
            dB[cf] = pbf2(acc[cf][2], acc[cf][3]);
        }
        // shuffle -> A-frag: lane (lr,lg) gets hj[16w+lr][32ks+8lg .. +8)
        bf16x8 ajf[2];
#pragma unroll
        for (int ks = 0; ks < 2; ++ks) {
            unsigned d0a = __shfl(dA[2 * ks],     s0), d0b = __shfl(dA[2 * ks + 1], s0);
            unsigned d1a = __shfl(dB[2 * ks],     s0), d1b = __shfl(dB[2 * ks + 1], s0);
            unsigned d2a = __shfl(dA[2 * ks],     s1), d2b = __shfl(dA[2 * ks + 1], s1);
            unsigned d3a = __shfl(dB[2 * ks],     s1), d3b = __shfl(dB[2 * ks + 1], s1);
            uint4 u;
            u.x = hicf ? d0b : d0a;
            u.y = hicf ? d1b : d1a;
            u.z = hicf ? d2b : d2a;
            u.w = hicf ? d3b : d3a;
            ajf[ks] = __builtin_bit_cast(bf16x8, u);
        }

        // ---- logits: D[j][i], j = j0+16w+4lg+r, i = i0+16itt+lr ----
        f32x4 lac[4];
#pragma unroll
        for (int itt = 0; itt < 4; ++itt) lac[itt] = (f32x4){0.f, 0.f, 0.f, 0.f};
#pragma unroll
        for (int ks = 0; ks < 2; ++ks)
#pragma unroll
            for (int itt = 0; itt < 4; ++itt)
                lac[itt] = __builtin_amdgcn_mfma_f32_16x16x32_bf16(
                    ajf[ks], hifr[itt][ks], lac[itt], 0, 0, 0);

        // ---- fused epilogue ----
        const int colbase = j0 + 16 * w + 4 * lg;
#pragma unroll
        for (int itt = 0; itt < 4; ++itt) {
            const int row = i0 + 16 * itt + lr;
            f32x4 ov;
#pragma unroll
            for (int r = 0; r < 4; ++r) {
                float x  = lac[itt][r] * 0.125f;      // / sqrt(64), tau = 1
                float ax = fabsf(x);
                float nl = __logf(1.0f + __expf(-ax));
                bool diag = (row == colbase + r);
                ov[r] = (diag || x > 0.f) ? 1.f : 0.f;
                if (!diag) lsum -= nl;
            }
            __builtin_nontemporal_store(ov,
                reinterpret_cast<f32x4*>(&Aout[((size_t)b * NPTS + row) * NPTS + colbase]));
        }
    }

    // deterministic block reduction of lsum
#pragma unroll
    for (int off = 32; off > 0; off >>= 1) lsum += __shfl_down(lsum, off);
    if (l == 0) red[w] = lsum;
    __syncthreads();
    if (t == 0) {
        float s = (red[0] + red[1]) + (red[2] + red[3]);
        partials[b * 16 + rem] = s;
    }
}

// ---------------------------------------------------------------------------
// K3: probs[b] = sum of 16 block partials (deterministic)
// ---------------------------------------------------------------------------
__global__ __launch_bounds__(64) void k3_reduce(const float* __restrict__ partials,
                                                float* __restrict__ probs) {
    int b = blockIdx.x;
    float s = (threadIdx.x < 16) ? partials[b * 16 + threadIdx.x] : 0.f;
#pragma unroll
    for (int off = 32; off > 0; off >>= 1) s += __shfl_down(s, off);
    if (threadIdx.x == 0) probs[b] = s;
}

extern "C" void kernel_launch(void* const* d_in, const int* in_sizes, int n_in,
                              void* d_out, int out_size, void* d_ws, size_t ws_size,
                              hipStream_t stream) {
    const float* h  = (const float*)d_in[0];
    const float* al = (const float*)d_in[1];
    const float* bl = (const float*)d_in[2];
    float* out = (float*)d_out;

    ushort* wt      = (ushort*)d_ws;                 // 128*256 bf16 (64 KB)
    float* partials = (float*)(wt + 128 * FOBS);     // 512 f32

    k0_wt<<<128, 256, 0, stream>>>(al, bl, wt);

    kU<<<512, 256, 0, stream>>>(h, wt, out, partials);

    k3_reduce<<<BATCH, 64, 0, stream>>>(partials, out + A_ELEMS);
}